// Round 5
// baseline (202.115 us; speedup 1.0000x reference)
//
#include <hip/hip_runtime.h>
#include <hip/hip_bf16.h>
#include <math.h>

// Problem constants
#define B_  8
#define T_  2048
#define C_  768
#define HS_ 256

// Wave-autonomous flash: each WAVE owns (batch b, 32-row q-granule g32,
// 256-key chunk ci). k-tile = 32 keys; chunk = 8 k-tiles. Granule g32
// (0..63) needs g32+1 k-tiles -> nchunks(g) = (g>>3)+1; per-batch waves =
// 8*(1+..+8) = 288; total waves = 2304 = 576 blocks x 4 waves. NO barriers:
// per-wave K/V staged into a private 16 KB LDS buffer (K/V time-share).
#define WAVES_PER_BATCH 288
#define NSLOT (WAVES_PER_BATCH * B_)   // 2304

typedef float  f32x4  __attribute__((ext_vector_type(4)));
typedef __bf16 bf16x8 __attribute__((ext_vector_type(8)));
typedef __bf16 bf16x4 __attribute__((ext_vector_type(4)));
typedef __bf16 bf16x2 __attribute__((ext_vector_type(2)));

#define MFMA16(a, b, c) __builtin_amdgcn_mfma_f32_16x16x32_bf16((a), (b), (c), 0, 0, 0)

// global->LDS async copy, 16B per lane (dest = wave-uniform base + lane*16)
#define GLOAD_LDS16(gp, lp)                                                     \
    __builtin_amdgcn_global_load_lds(                                           \
        (const __attribute__((address_space(1))) void*)(gp),                    \
        (__attribute__((address_space(3))) void*)(lp), 16, 0, 0)

// ---------------------------------------------------------------------------
// Kernel 0: prep = x cast (blocks 0..6143) + weight transpose (6144..6431).
// ---------------------------------------------------------------------------
__global__ __launch_bounds__(256) void prep_kernel(const float* __restrict__ x,
                                                   const float* __restrict__ Wq,
                                                   const float* __restrict__ Wk,
                                                   const float* __restrict__ Wv,
                                                   __bf16* __restrict__ xb,
                                                   __bf16* __restrict__ wt_all,
                                                   float qscale) {
    const int bid = blockIdx.x;
    if (bid < 6144) {
        size_t i = ((size_t)bid * 256 + threadIdx.x) * 8;
        f32x4 a = *(const f32x4*)(x + i);
        f32x4 b = *(const f32x4*)(x + i + 4);
        bf16x8 o;
        o[0] = (__bf16)a[0]; o[1] = (__bf16)a[1]; o[2] = (__bf16)a[2]; o[3] = (__bf16)a[3];
        o[4] = (__bf16)b[0]; o[5] = (__bf16)b[1]; o[6] = (__bf16)b[2]; o[7] = (__bf16)b[3];
        *(bf16x8*)(xb + i) = o;
    } else {
        int idx = (bid - 6144) * 256 + threadIdx.x;   // [0, 73728)
        int n   = idx & 255;
        int t   = idx >> 8;          // [0, 288) = mat*96 + k8
        int mat = t / 96;
        int k8  = t - mat * 96;
        const float* W = (mat == 0) ? Wq : ((mat == 1) ? Wk : Wv);
        float scale = (mat == 0) ? qscale : 1.0f;
        bf16x8 o;
#pragma unroll
        for (int j = 0; j < 8; j++)
            o[j] = (__bf16)(W[(k8 * 8 + j) * HS_ + n] * scale);
        *(bf16x8*)&wt_all[((size_t)mat * HS_ + n) * C_ + k8 * 8] = o;
    }
}

// ---------------------------------------------------------------------------
// Kernel 2: fused QKV GEMM. BK=32, double-buffered LDS, one barrier/iter.
//   Q/K tiles: swapped operands (C rows carry d) -> coalesced bf16x4 stores.
// Fragment layouts (element index, all *8 = 8 bf16 per lane slot):
//   Q: ((((b*32+qt)*4 + w16)*8 + ks )*64 + lane)   lane&15 = q, quad = (d>>3)&3, j = d&7
//   K: ((((b*32+kt)*8 + ks )*4 + ns )*64 + lane)   lane&15 = s, quad = (d>>3)&3, j = d&7
//   V: ((((b*32+kt)*2 + ks2)*16 + ntv)*64 + lane)  lane&15 = d, quad = (s>>3)&3, j = s&7
// ---------------------------------------------------------------------------
__global__ __launch_bounds__(256) void proj_kernel(const __bf16* __restrict__ xb,
                                                   const __bf16* __restrict__ wt,
                                                   __bf16* __restrict__ qf_,
                                                   __bf16* __restrict__ kf_,
                                                   __bf16* __restrict__ vf_) {
    __shared__ alignas(16) __bf16 ldsA[2][128 * 32];   // 2 x 8 KB
    __shared__ alignas(16) __bf16 ldsB[2][128 * 32];   // 2 x 8 KB

    const int tid  = threadIdx.x;
    const int w    = tid >> 6;
    const int lane = tid & 63;
    const int cm   = lane & 15;
    const int quad = lane >> 4;
    const int wm   = w & 1;
    const int wn   = w >> 1;
    const int m0   = blockIdx.x * 128;
    const int n0   = blockIdx.y * 128;
    const int mat  = n0 >> 8;                 // 0=Q 1=K 2=V

    f32x4 acc[4][4];
#pragma unroll
    for (int i = 0; i < 4; i++)
#pragma unroll
        for (int j = 0; j < 4; j++) acc[i][j] = (f32x4){0.f, 0.f, 0.f, 0.f};

    // prologue: stage k-iter 0 into buffer 0
#pragma unroll
    for (int h = 0; h < 2; h++) {
        int c = tid + h * 256;   // 512 chunks: row = c>>2, col granule = (c&3)*8
        GLOAD_LDS16(xb + (size_t)(m0 + (c >> 2)) * C_ + (c & 3) * 8, &ldsA[0][c * 8]);
        GLOAD_LDS16(wt + (size_t)(n0 + (c >> 2)) * C_ + (c & 3) * 8, &ldsB[0][c * 8]);
    }

    for (int kt = 0; kt < 24; kt++) {
        const int cur = kt & 1;
        __syncthreads();   // drains vmcnt -> buf[cur] staged; prev reads done

        if (kt < 23) {
            const int k0 = (kt + 1) * 32;
#pragma unroll
            for (int h = 0; h < 2; h++) {
                int c = tid + h * 256;
                GLOAD_LDS16(xb + (size_t)(m0 + (c >> 2)) * C_ + k0 + (c & 3) * 8,
                            &ldsA[cur ^ 1][c * 8]);
                GLOAD_LDS16(wt + (size_t)(n0 + (c >> 2)) * C_ + k0 + (c & 3) * 8,
                            &ldsB[cur ^ 1][c * 8]);
            }
        }

        bf16x8 af[4], bfr[4];
#pragma unroll
        for (int mt = 0; mt < 4; mt++)
            af[mt] = *(const bf16x8*)&ldsA[cur][(wm * 64 + mt * 16 + cm) * 32 + quad * 8];
#pragma unroll
        for (int nt = 0; nt < 4; nt++)
            bfr[nt] = *(const bf16x8*)&ldsB[cur][(wn * 64 + nt * 16 + cm) * 32 + quad * 8];
        if (mat < 2) {
#pragma unroll
            for (int dt = 0; dt < 4; dt++)
#pragma unroll
                for (int qt2 = 0; qt2 < 4; qt2++)
                    acc[dt][qt2] = MFMA16(bfr[dt], af[qt2], acc[dt][qt2]);
        } else {
#pragma unroll
            for (int mt = 0; mt < 4; mt++)
#pragma unroll
                for (int nt = 0; nt < 4; nt++)
                    acc[mt][nt] = MFMA16(af[mt], bfr[nt], acc[mt][nt]);
        }
    }

    const int dBase = (n0 & 255) + wn * 64;
    const int b     = m0 >> 11;
    if (mat < 2) {
        const int rt2 = ((m0 & 2047) >> 6) + wm;   // 64-row tile within batch
        __bf16* dst = (mat == 0) ? qf_ : kf_;
#pragma unroll
        for (int dt = 0; dt < 4; dt++)
#pragma unroll
            for (int qt2 = 0; qt2 < 4; qt2++) {
                int d0    = dBase + dt * 16 + quad * 4;   // d of reg i = d0 + i
                int ksq   = d0 >> 5;
                int quadp = (d0 >> 3) & 3;
                int j0    = d0 & 7;
                size_t addr;
                if (mat == 0)
                    addr = ((((size_t)(b * 32 + rt2) * 4 + qt2) * 8 + ksq) * 64
                            + quadp * 16 + cm) * 8 + j0;
                else
                    addr = ((((size_t)(b * 32 + rt2) * 8 + ksq) * 4 + qt2) * 64
                            + quadp * 16 + cm) * 8 + j0;
                bf16x4 v4;
                v4[0] = (__bf16)acc[dt][qt2][0]; v4[1] = (__bf16)acc[dt][qt2][1];
                v4[2] = (__bf16)acc[dt][qt2][2]; v4[3] = (__bf16)acc[dt][qt2][3];
                *(bf16x4*)(dst + addr) = v4;
            }
    } else {
        const int rt = ((m0 & 2047) + wm * 64) >> 6;
#pragma unroll
        for (int mt = 0; mt < 4; mt++) {
            int ks2   = (mt >> 1) & 1;
            int quadF = (mt & 1) * 2 + (quad >> 1);
            int jb    = (quad & 1) * 4;
#pragma unroll
            for (int nt = 0; nt < 4; nt++) {
                int ntv = (dBase >> 4) + nt;
                size_t idx = ((((size_t)(b * 32 + rt) * 2 + ks2) * 16 + ntv) * 64
                              + quadF * 16 + cm) * 8 + jb;
                bf16x4 v4;
                v4[0] = (__bf16)acc[mt][nt][0]; v4[1] = (__bf16)acc[mt][nt][1];
                v4[2] = (__bf16)acc[mt][nt][2]; v4[3] = (__bf16)acc[mt][nt][3];
                *(bf16x4*)(vf_ + idx) = v4;
            }
        }
    }
}

// ---------------------------------------------------------------------------
// Kernel 3a: WAVE-AUTONOMOUS split-K causal flash partial (R15).
//   R13/R14 post-mortems: per-tile cost ~3500-5700 cyc is the barrier-locked
//   critical path (all 4 waves in identical dependent phases; pipes <15%
//   busy). Fix: NO barriers. Each wave owns (b, g32, chunk) with a private
//   16 KB LDS buffer; K and V time-share it (stage K -> read K to regs ->
//   lgkmcnt(0) -> stage V overlapped with softmax -> vmcnt(0) -> PV).
//   vmcnt/lgkmcnt are per-wave, global_load_lds dest is per-wave -> waves
//   fully independent; 8 waves/CU at uncorrelated phases fill the pipes.
//   LDS/block = 4x(16KB + 2KB P) = 72 KB -> 2 blocks/CU.
// ---------------------------------------------------------------------------
__global__ __launch_bounds__(256, 2) void flash_part(const __bf16* __restrict__ qf_,
                                                     const __bf16* __restrict__ kf_,
                                                     const __bf16* __restrict__ vf_,
                                                     __bf16* __restrict__ Opart,
                                                     float* __restrict__ mpart,
                                                     float* __restrict__ lpart) {
    __shared__ alignas(16) __bf16 ldsKV[4][8192];    // 16 KB per wave (K/V share)
    __shared__ alignas(16) __bf16 ldsP[4][2][512];   // per-wave P, 2 q-groups

    const int tid  = threadIdx.x;
    const int w    = tid >> 6;       // 0..3
    const int lane = tid & 63;
    const int cm   = lane & 15;      // = q column (within 16-row group)
    const int quad = lane >> 4;

    const int pid = blockIdx.x;                       // [0, 576)
    const int b   = pid & 7;                          // batch -> XCD affinity
    const int r   = (WAVES_PER_BATCH - 1) - ((pid >> 3) * 4 + w);   // heavy first
    int g32 = 0, ci = 0;
    {
        int rr = r;
        for (int j = 0; j < 64; j++) {
            int c = (j >> 3) + 1;                     // chunks for granule j
            if (rr < c) { g32 = j; ci = rr; break; }
            rr -= c;
        }
    }
    const int lpid     = b * WAVES_PER_BATCH + r;     // output slot (32 rows)
    const int kt_begin = ci * 8;                      // 32-key tiles
    const int kt_end   = min(kt_begin + 8, g32 + 1);

    __bf16* myKV = &ldsKV[w][0];

    // Q fragments: rows [g32*32, +32) = 2 x 16-row groups.
    bf16x8 qf2[2][8];
#pragma unroll
    for (int qg = 0; qg < 2; qg++) {
        int g16 = g32 * 2 + qg;
        const __bf16* qp = qf_ + (((size_t)(b * 32 + (g16 >> 2)) * 4 + (g16 & 3)) * 8) * 512
                           + lane * 8;
#pragma unroll
        for (int ks = 0; ks < 8; ks++) qf2[qg][ks] = *(const bf16x8*)(qp + ks * 512);
    }

    // per-wave staging: 16 x 1KB instructions each (dest = base + lane*16)
    auto stageK = [&](int kt) {
        const int kt64 = kt >> 1, kh = kt & 1;
        const __bf16* kgb = kf_ + (((size_t)(b * 32 + kt64) * 8) * 4 + kh * 2) * 512;
#pragma unroll
        for (int u = 0; u < 16; u++)
            GLOAD_LDS16(kgb + (size_t)(u >> 1) * 2048 + (u & 1) * 512 + lane * 8,
                        myKV + u * 512);
    };
    auto stageV = [&](int kt) {
        const __bf16* vgb = vf_ + ((size_t)(b * 64 + kt) * 16) * 512;
#pragma unroll
        for (int u = 0; u < 16; u++)
            GLOAD_LDS16(vgb + (size_t)u * 512 + lane * 8, myKV + u * 512);
    };

    f32x4 accO[2][16];   // accO[qg][nt][i]: d = nt*16 + quad*4 + i, q = qg*16+cm
#pragma unroll
    for (int qg = 0; qg < 2; qg++)
#pragma unroll
        for (int i = 0; i < 16; i++) accO[qg][i] = (f32x4){0.f, 0.f, 0.f, 0.f};
    float mi[2] = {0.f, 0.f}, li[2] = {0.f, 0.f};

    const int wrow = g32 * 32;

    stageK(kt_begin);
    for (int kt = kt_begin; kt < kt_end; kt++) {
        asm volatile("s_waitcnt vmcnt(0)" ::: "memory");   // K tile landed

        // ---- St = K Q^T  (32 s x 32 q per wave) ----
        f32x4 s[2][2];   // [ns][qg]
#pragma unroll
        for (int ns = 0; ns < 2; ns++)
#pragma unroll
            for (int qg = 0; qg < 2; qg++) s[ns][qg] = (f32x4){0.f, 0.f, 0.f, 0.f};
        __builtin_amdgcn_s_setprio(1);
#pragma unroll
        for (int ns = 0; ns < 2; ns++)
#pragma unroll
            for (int ks = 0; ks < 8; ks++) {
                bf16x8 kfr = *(const bf16x8*)&myKV[(ks * 2 + ns) * 512 + lane * 8];
                s[ns][0] = MFMA16(kfr, qf2[0][ks], s[ns][0]);
                s[ns][1] = MFMA16(kfr, qf2[1][ks], s[ns][1]);
            }
        __builtin_amdgcn_s_setprio(0);
        // all K ds_reads returned -> buffer reusable; stage V under softmax
        asm volatile("s_waitcnt lgkmcnt(0)" ::: "memory");
        stageV(kt);

        // ---- causal mask ----
        if (kt * 32 + 31 > wrow) {
#pragma unroll
            for (int qg = 0; qg < 2; qg++) {
                int qglob = wrow + qg * 16 + cm;
#pragma unroll
                for (int ns = 0; ns < 2; ns++)
#pragma unroll
                    for (int i = 0; i < 4; i++)
                        if (kt * 32 + ns * 16 + quad * 4 + i > qglob)
                            s[ns][qg][i] = -__builtin_inff();
            }
        }
        // ---- fixed-anchor softmax: establish m once (first tile) ----
        if (kt == kt_begin) {
#pragma unroll
            for (int qg = 0; qg < 2; qg++) {
                float pm = -__builtin_inff();
#pragma unroll
                for (int ns = 0; ns < 2; ns++)
#pragma unroll
                    for (int i = 0; i < 4; i++) pm = fmaxf(pm, s[ns][qg][i]);
                pm = fmaxf(pm, __shfl_xor(pm, 16));
                pm = fmaxf(pm, __shfl_xor(pm, 32));
                mi[qg] = pm;
            }
        }
        float p[2][2][4];   // [qg][ns][i]
        float rs[2] = {0.f, 0.f};
#pragma unroll
        for (int qg = 0; qg < 2; qg++)
#pragma unroll
            for (int ns = 0; ns < 2; ns++)
#pragma unroll
                for (int i = 0; i < 4; i++) {
                    p[qg][ns][i] = exp2f(s[ns][qg][i] - mi[qg]);
                    rs[qg] += p[qg][ns][i];
                }
#pragma unroll
        for (int qg = 0; qg < 2; qg++) {
            rs[qg] += __shfl_xor(rs[qg], 16);
            rs[qg] += __shfl_xor(rs[qg], 32);
            li[qg] += rs[qg];
        }

        // ---- P -> private per-wave LDS in PV B-operand layout ----
#pragma unroll
        for (int qg = 0; qg < 2; qg++)
#pragma unroll
            for (int ns = 0; ns < 2; ns++)
#pragma unroll
                for (int i2 = 0; i2 < 2; i2++) {
                    bf16x2 d2;
                    d2[0] = (__bf16)p[qg][ns][2 * i2];
                    d2[1] = (__bf16)p[qg][ns][2 * i2 + 1];
                    int off = ((ns * 2 + (quad >> 1)) * 16 + cm) * 8
                              + (quad & 1) * 4 + i2 * 2;
                    *(bf16x2*)&ldsP[w][qg][off] = d2;
                }
        bf16x8 pf0 = *(const bf16x8*)&ldsP[w][0][(quad * 16 + cm) * 8];
        bf16x8 pf1 = *(const bf16x8*)&ldsP[w][1][(quad * 16 + cm) * 8];

        asm volatile("s_waitcnt vmcnt(0)" ::: "memory");   // V tile landed
        // ---- O += V^T-frag x P-frag ----
        __builtin_amdgcn_s_setprio(1);
#pragma unroll
        for (int nt = 0; nt < 16; nt++) {
            bf16x8 vfr = *(const bf16x8*)&myKV[nt * 512 + lane * 8];
            accO[0][nt] = MFMA16(vfr, pf0, accO[0][nt]);
            accO[1][nt] = MFMA16(vfr, pf1, accO[1][nt]);
        }
        __builtin_amdgcn_s_setprio(0);
        // all V ds_reads returned -> buffer reusable; prefetch next K
        asm volatile("s_waitcnt lgkmcnt(0)" ::: "memory");
        if (kt + 1 < kt_end) stageK(kt + 1);
    }

    // ---- epilogue: coalesced bf16x4 stores + fp32 (m, l) ----
#pragma unroll
    for (int qg = 0; qg < 2; qg++) {
        __bf16* op = Opart + ((size_t)lpid * 32 + qg * 16 + cm) * HS_;
#pragma unroll
        for (int nt = 0; nt < 16; nt++) {
            bf16x4 v4;
            v4[0] = (__bf16)accO[qg][nt][0]; v4[1] = (__bf16)accO[qg][nt][1];
            v4[2] = (__bf16)accO[qg][nt][2]; v4[3] = (__bf16)accO[qg][nt][3];
            *(bf16x4*)(op + nt * 16 + quad * 4) = v4;
        }
        if (quad == 0) {
            mpart[lpid * 32 + qg * 16 + cm] = mi[qg];
            lpart[lpid * 32 + qg * 16 + cm] = li[qg];
        }
    }
}

// ---------------------------------------------------------------------------
// Kernel 3b: combine partials.  Grid (512): block = (b, g32), 32 rows.
//   nc(g) = (g>>3)+1 partial slots; cum(g) = 4t(t+1) + (g&7)(t+1), t=g>>3.
// ---------------------------------------------------------------------------
__global__ __launch_bounds__(256) void flash_combine(const __bf16* __restrict__ Opart,
                                                     const float* __restrict__ mpart,
                                                     const float* __restrict__ lpart,
                                                     float* __restrict__ out) {
    const int b    = blockIdx.x >> 6;
    const int g    = blockIdx.x & 63;
    const int t    = g >> 3;
    const int nc   = t + 1;
    const int pid0 = b * WAVES_PER_BATCH + 4 * t * (t + 1) + (g & 7) * (t + 1);

    const int tid = threadIdx.x;
    const int col = (tid & 63) * 4;
    const int r0  = (tid >> 6) * 8;     // 8 rows per 64-lane group

    float ms[8];
#pragma unroll
    for (int i = 0; i < 8; i++) ms[i] = -__builtin_inff();
    for (int c = 0; c < nc; c++)
#pragma unroll
        for (int i = 0; i < 8; i++)
            ms[i] = fmaxf(ms[i], mpart[(pid0 + c) * 32 + r0 + i]);

    f32x4 acc[8];
    float lt[8];
#pragma unroll
    for (int i = 0; i < 8; i++) { acc[i] = (f32x4){0.f, 0.f, 0.f, 0.f}; lt[i] = 0.f; }

    for (int c = 0; c < nc; c++) {
#pragma unroll
        for (int i = 0; i < 8; i++) {
            float sc = exp2f(mpart[(pid0 + c) * 32 + r0 + i] - ms[i]);
            lt[i] += lpart[(pid0 + c) * 32 + r0 + i] * sc;
            bf16x4 o = *(const bf16x4*)(Opart
                        + ((size_t)(pid0 + c) * 32 + r0 + i) * HS_ + col);
            acc[i][0] += (float)o[0] * sc; acc[i][1] += (float)o[1] * sc;
            acc[i][2] += (float)o[2] * sc; acc[i][3] += (float)o[3] * sc;
        }
    }
#pragma unroll
    for (int i = 0; i < 8; i++) {
        float inv = 1.0f / lt[i];
        f32x4 res = (f32x4){acc[i][0] * inv, acc[i][1] * inv,
                            acc[i][2] * inv, acc[i][3] * inv};
        *(f32x4*)(out + ((size_t)(b * T_ + g * 32 + r0 + i)) * HS_ + col) = res;
    }
}

// ---------------------------------------------------------------------------
extern "C" void kernel_launch(void* const* d_in, const int* in_sizes, int n_in,
                              void* d_out, int out_size, void* d_ws, size_t ws_size,
                              hipStream_t stream) {
    const float* x  = (const float*)d_in[0];
    const float* Wq = (const float*)d_in[1];
    const float* Wk = (const float*)d_in[2];
    const float* Wv = (const float*)d_in[3];
    float* out = (float*)d_out;

    char* ws = (char*)d_ws;
    size_t off = 0;
    __bf16* wt_all = (__bf16*)(ws + off); off += 1179648;
    __bf16* qfrag  = (__bf16*)(ws + off); off += 8388608;
    __bf16* kfrag  = (__bf16*)(ws + off); off += 8388608;
    __bf16* vfrag  = (__bf16*)(ws + off); off += 8388608;
    __bf16* xb     = (__bf16*)(ws + off);              // union with Opart
    __bf16* Opart  = (__bf16*)(ws + off); off += (size_t)NSLOT * 32 * HS_ * 2;
    float*  mpart  = (float*)(ws + off);  off += (size_t)NSLOT * 32 * 4;
    float*  lpart  = (float*)(ws + off);

    float qscale = 1.4426950408889634f / sqrtf((float)C_);

    prep_kernel<<<dim3(6432), 256, 0, stream>>>(x, Wq, Wk, Wv, xb, wt_all, qscale);
    proj_kernel<<<dim3(128, 6), 256, 0, stream>>>(xb, wt_all, qfrag, kfrag, vfrag);
    flash_part<<<dim3(576), 256, 0, stream>>>(qfrag, kfrag, vfrag, Opart, mpart, lpart);
    flash_combine<<<dim3(512), 256, 0, stream>>>(Opart, mpart, lpart, out);
}

// Round 7
// 195.049 us; speedup vs baseline: 1.0362x; 1.0362x over previous
//
#include <hip/hip_runtime.h>
#include <hip/hip_bf16.h>
#include <math.h>

// Problem constants
#define B_  8
#define T_  2048
#define C_  768
#define HS_ 256

// Split-K flash: q-block = 64 rows, k-tile = 32 keys, chunk = 8 k-tiles
// (256 keys). q-block qb (0..31) has 2qb+2 k-tiles; chunks(qb) = (qb>>2)+1;
// per-batch chunk total = 144; blocks = 8 * 144 = 1152.
// R16: R12 body (36 KB LDS, proven 42us) + fine chunks + launch_bounds(256,4)
// -> 4 blocks/CU resident (dur tracked 1/occupancy across R12-R15).
#define CHUNKS_PER_BATCH 144
#define NSLOT (CHUNKS_PER_BATCH * B_)   // 1152

typedef float  f32x4  __attribute__((ext_vector_type(4)));
typedef __bf16 bf16x8 __attribute__((ext_vector_type(8)));
typedef __bf16 bf16x4 __attribute__((ext_vector_type(4)));
typedef __bf16 bf16x2 __attribute__((ext_vector_type(2)));

#define MFMA16(a, b, c) __builtin_amdgcn_mfma_f32_16x16x32_bf16((a), (b), (c), 0, 0, 0)

// global->LDS async copy, 16B per lane (dest = wave-uniform base + lane*16)
#define GLOAD_LDS16(gp, lp)                                                     \
    __builtin_amdgcn_global_load_lds(                                           \
        (const __attribute__((address_space(1))) void*)(gp),                    \
        (__attribute__((address_space(3))) void*)(lp), 16, 0, 0)

// cumulative chunk count before q-block qb (8-tile chunks):
// g=qb>>2 -> 2g(g+1) + (qb&3)(g+1)
__device__ __forceinline__ int chunk_cum64(int qb) {
    int g = qb >> 2;
    return 2 * g * (g + 1) + (qb & 3) * (g + 1);
}

// ---------------------------------------------------------------------------
// Kernel 0: prep = x cast (blocks 0..6143) + weight transpose (6144..6431).
// ---------------------------------------------------------------------------
__global__ __launch_bounds__(256) void prep_kernel(const float* __restrict__ x,
                                                   const float* __restrict__ Wq,
                                                   const float* __restrict__ Wk,
                                                   const float* __restrict__ Wv,
                                                   __bf16* __restrict__ xb,
                                                   __bf16* __restrict__ wt_all,
                                                   float qscale) {
    const int bid = blockIdx.x;
    if (bid < 6144) {
        size_t i = ((size_t)bid * 256 + threadIdx.x) * 8;
        f32x4 a = *(const f32x4*)(x + i);
        f32x4 b = *(const f32x4*)(x + i + 4);
        bf16x8 o;
        o[0] = (__bf16)a[0]; o[1] = (__bf16)a[1]; o[2] = (__bf16)a[2]; o[3] = (__bf16)a[3];
        o[4] = (__bf16)b[0]; o[5] = (__bf16)b[1]; o[6] = (__bf16)b[2]; o[7] = (__bf16)b[3];
        *(bf16x8*)(xb + i) = o;
    } else {
        int idx = (bid - 6144) * 256 + threadIdx.x;   // [0, 73728)
        int n   = idx & 255;
        int t   = idx >> 8;          // [0, 288) = mat*96 + k8
        int mat = t / 96;
        int k8  = t - mat * 96;
        const float* W = (mat == 0) ? Wq : ((mat == 1) ? Wk : Wv);
        float scale = (mat == 0) ? qscale : 1.0f;
        bf16x8 o;
#pragma unroll
        for (int j = 0; j < 8; j++)
            o[j] = (__bf16)(W[(k8 * 8 + j) * HS_ + n] * scale);
        *(bf16x8*)&wt_all[((size_t)mat * HS_ + n) * C_ + k8 * 8] = o;
    }
}

// ---------------------------------------------------------------------------
// Kernel 2: fused QKV GEMM. BK=32, double-buffered LDS, one barrier/iter.
//   Q/K tiles: swapped operands (C rows carry d) -> coalesced bf16x4 stores.
// Fragment layouts (element index, all *8 = 8 bf16 per lane slot):
//   Q: ((((b*32+qt)*4 + w16)*8 + ks )*64 + lane)   lane&15 = q, quad = (d>>3)&3, j = d&7
//   K: ((((b*32+kt)*8 + ks )*4 + ns )*64 + lane)   lane&15 = s, quad = (d>>3)&3, j = d&7
//   V: ((((b*32+kt)*2 + ks2)*16 + ntv)*64 + lane)  lane&15 = d, quad = (s>>3)&3, j = s&7
// ---------------------------------------------------------------------------
__global__ __launch_bounds__(256) void proj_kernel(const __bf16* __restrict__ xb,
                                                   const __bf16* __restrict__ wt,
                                                   __bf16* __restrict__ qf_,
                                                   __bf16* __restrict__ kf_,
                                                   __bf16* __restrict__ vf_) {
    __shared__ alignas(16) __bf16 ldsA[2][128 * 32];   // 2 x 8 KB
    __shared__ alignas(16) __bf16 ldsB[2][128 * 32];   // 2 x 8 KB

    const int tid  = threadIdx.x;
    const int w    = tid >> 6;
    const int lane = tid & 63;
    const int cm   = lane & 15;
    const int quad = lane >> 4;
    const int wm   = w & 1;
    const int wn   = w >> 1;
    const int m0   = blockIdx.x * 128;
    const int n0   = blockIdx.y * 128;
    const int mat  = n0 >> 8;                 // 0=Q 1=K 2=V

    f32x4 acc[4][4];
#pragma unroll
    for (int i = 0; i < 4; i++)
#pragma unroll
        for (int j = 0; j < 4; j++) acc[i][j] = (f32x4){0.f, 0.f, 0.f, 0.f};

    // prologue: stage k-iter 0 into buffer 0
#pragma unroll
    for (int h = 0; h < 2; h++) {
        int c = tid + h * 256;   // 512 chunks: row = c>>2, col granule = (c&3)*8
        GLOAD_LDS16(xb + (size_t)(m0 + (c >> 2)) * C_ + (c & 3) * 8, &ldsA[0][c * 8]);
        GLOAD_LDS16(wt + (size_t)(n0 + (c >> 2)) * C_ + (c & 3) * 8, &ldsB[0][c * 8]);
    }

    for (int kt = 0; kt < 24; kt++) {
        const int cur = kt & 1;
        __syncthreads();   // drains vmcnt -> buf[cur] staged; prev reads done

        if (kt < 23) {
            const int k0 = (kt + 1) * 32;
#pragma unroll
            for (int h = 0; h < 2; h++) {
                int c = tid + h * 256;
                GLOAD_LDS16(xb + (size_t)(m0 + (c >> 2)) * C_ + k0 + (c & 3) * 8,
                            &ldsA[cur ^ 1][c * 8]);
                GLOAD_LDS16(wt + (size_t)(n0 + (c >> 2)) * C_ + k0 + (c & 3) * 8,
                            &ldsB[cur ^ 1][c * 8]);
            }
        }

        bf16x8 af[4], bfr[4];
#pragma unroll
        for (int mt = 0; mt < 4; mt++)
            af[mt] = *(const bf16x8*)&ldsA[cur][(wm * 64 + mt * 16 + cm) * 32 + quad * 8];
#pragma unroll
        for (int nt = 0; nt < 4; nt++)
            bfr[nt] = *(const bf16x8*)&ldsB[cur][(wn * 64 + nt * 16 + cm) * 32 + quad * 8];
        if (mat < 2) {
#pragma unroll
            for (int dt = 0; dt < 4; dt++)
#pragma unroll
                for (int qt2 = 0; qt2 < 4; qt2++)
                    acc[dt][qt2] = MFMA16(bfr[dt], af[qt2], acc[dt][qt2]);
        } else {
#pragma unroll
            for (int mt = 0; mt < 4; mt++)
#pragma unroll
                for (int nt = 0; nt < 4; nt++)
                    acc[mt][nt] = MFMA16(af[mt], bfr[nt], acc[mt][nt]);
        }
    }

    const int dBase = (n0 & 255) + wn * 64;
    const int b     = m0 >> 11;
    if (mat < 2) {
        const int rt2 = ((m0 & 2047) >> 6) + wm;   // 64-row tile within batch
        __bf16* dst = (mat == 0) ? qf_ : kf_;
#pragma unroll
        for (int dt = 0; dt < 4; dt++)
#pragma unroll
            for (int qt2 = 0; qt2 < 4; qt2++) {
                int d0    = dBase + dt * 16 + quad * 4;   // d of reg i = d0 + i
                int ksq   = d0 >> 5;
                int quadp = (d0 >> 3) & 3;
                int j0    = d0 & 7;
                size_t addr;
                if (mat == 0)
                    addr = ((((size_t)(b * 32 + rt2) * 4 + qt2) * 8 + ksq) * 64
                            + quadp * 16 + cm) * 8 + j0;
                else
                    addr = ((((size_t)(b * 32 + rt2) * 8 + ksq) * 4 + qt2) * 64
                            + quadp * 16 + cm) * 8 + j0;
                bf16x4 v4;
                v4[0] = (__bf16)acc[dt][qt2][0]; v4[1] = (__bf16)acc[dt][qt2][1];
                v4[2] = (__bf16)acc[dt][qt2][2]; v4[3] = (__bf16)acc[dt][qt2][3];
                *(bf16x4*)(dst + addr) = v4;
            }
    } else {
        const int rt = ((m0 & 2047) + wm * 64) >> 6;
#pragma unroll
        for (int mt = 0; mt < 4; mt++) {
            int ks2   = (mt >> 1) & 1;
            int quadF = (mt & 1) * 2 + (quad >> 1);
            int jb    = (quad & 1) * 4;
#pragma unroll
            for (int nt = 0; nt < 4; nt++) {
                int ntv = (dBase >> 4) + nt;
                size_t idx = ((((size_t)(b * 32 + rt) * 2 + ks2) * 16 + ntv) * 64
                              + quadF * 16 + cm) * 8 + jb;
                bf16x4 v4;
                v4[0] = (__bf16)acc[mt][nt][0]; v4[1] = (__bf16)acc[mt][nt][1];
                v4[2] = (__bf16)acc[mt][nt][2]; v4[3] = (__bf16)acc[mt][nt][3];
                *(bf16x4*)(vf_ + idx) = v4;
            }
        }
    }
}

// ---------------------------------------------------------------------------
// Kernel 3a: split-K causal flash partial — R16 (resubmit): EXACT R12 body
//   (36 KB LDS, single-buffered K/V, 2 barriers/tile, block-shared staging)
//   + 8-tile (256-key) chunks -> 1152 blocks + __launch_bounds__(256,4) ->
//   4 blocks/CU resident (R12-R15 post-mortems: dur ~ 700/OccupancyPercent;
//   occupancy is the only lever that moved this kernel). Fixed-anchor
//   softmax, per-lane (q = cm), no rescale; P private per wave (1 KB).
// ---------------------------------------------------------------------------
__global__ __launch_bounds__(256, 4) void flash_part(const __bf16* __restrict__ qf_,
                                                     const __bf16* __restrict__ kf_,
                                                     const __bf16* __restrict__ vf_,
                                                     __bf16* __restrict__ Opart,
                                                     float* __restrict__ mpart,
                                                     float* __restrict__ lpart) {
    __shared__ alignas(16) __bf16 ldsK[8 * 2 * 64 * 8];   // [ks8][ns2][lane]x8 = 16 KB
    __shared__ alignas(16) __bf16 ldsV[16 * 64 * 8];      // [ntv16][lane]x8  = 16 KB
    __shared__ alignas(16) __bf16 ldsP[4][512];           // per-wave P (1 KB)

    const int tid  = threadIdx.x;
    const int w    = tid >> 6;       // 0..3
    const int lane = tid & 63;
    const int cm   = lane & 15;      // = q column
    const int quad = lane >> 4;

    const int pid  = blockIdx.x;                // [0, 1152)
    const int b    = pid & 7;                   // batch -> XCD spread
    const int r    = (CHUNKS_PER_BATCH - 1) - (pid >> 3);   // heavy chunks first
    int qb = 0, ci = 0;
    {
        int rr = r;
        for (int j = 0; j < 32; j++) {
            int c = (j >> 2) + 1;               // chunks for q-block j
            if (rr < c) { qb = j; ci = rr; break; }
            rr -= c;
        }
    }
    const int lpid = b * CHUNKS_PER_BATCH + r;  // output slot
    const int kt_begin = ci * 8;                        // 32-key tiles
    const int kt_end   = min(kt_begin + 8, 2 * qb + 2);

    // Q fragments (B-operand: lane&15 = q, quad*8+j = d), coalesced loads.
    const __bf16* qp = qf_ + (((size_t)(b * 32 + qb) * 4 + w) * 8) * 512 + lane * 8;
    bf16x8 qf[8];
#pragma unroll
    for (int ks = 0; ks < 8; ks++) qf[ks] = *(const bf16x8*)(qp + ks * 512);

    f32x4 accO[16];   // accO[nt][i]: d = nt*16 + quad*4 + i, q = cm
#pragma unroll
    for (int i = 0; i < 16; i++) accO[i] = (f32x4){0.f, 0.f, 0.f, 0.f};
    float mi = 0.f, li = 0.f;        // mi fixed after first tile

    const int wrow  = qb * 64 + w * 16;
    const int qglob = wrow + cm;

    for (int kt = kt_begin; kt < kt_end; kt++) {
        __syncthreads();   // (A) prior tile's LDS fully consumed

        // ---- stage K (16 KB) + V (16 KB) tile, async ----
        {
            const int kt64 = kt >> 1, kh = kt & 1;
            const __bf16* kgb = kf_ + (((size_t)(b * 32 + kt64) * 8) * 4 + kh * 2) * 512;
#pragma unroll
            for (int h = 0; h < 4; h++) {
                int g = h * 256 + tid;           // 16B slot id, 0..1023
                int ks = g >> 7, sub = g & 127;  // sub = ns2*64 + lane'
                GLOAD_LDS16(kgb + (size_t)ks * 4 * 512 + sub * 8,
                            ldsK + (h * 256 + w * 64) * 8);
            }
            const __bf16* vgb = vf_ + ((size_t)(b * 64 + kt) * 16) * 512;
#pragma unroll
            for (int h = 0; h < 4; h++) {
                int g = h * 256 + tid;           // ntv = g>>6, lane' = g&63
                GLOAD_LDS16(vgb + (size_t)g * 8,
                            ldsV + (h * 256 + w * 64) * 8);
            }
        }
        __syncthreads();   // (B) vmcnt drained -> K/V visible

        // ---- St = K Q^T  (32 s x 16 q per wave) ----
        f32x4 s[2];
#pragma unroll
        for (int i = 0; i < 2; i++) s[i] = (f32x4){0.f, 0.f, 0.f, 0.f};
        __builtin_amdgcn_s_setprio(1);
#pragma unroll
        for (int ns = 0; ns < 2; ns++)
#pragma unroll
            for (int ks = 0; ks < 8; ks++) {
                bf16x8 kfr = *(const bf16x8*)&ldsK[(ks * 2 + ns) * 512 + lane * 8];
                s[ns] = MFMA16(kfr, qf[ks], s[ns]);
            }
        __builtin_amdgcn_s_setprio(0);
        // ---- causal mask ----
        if (kt * 32 + 31 > wrow) {
#pragma unroll
            for (int ns = 0; ns < 2; ns++)
#pragma unroll
                for (int i = 0; i < 4; i++)
                    if (kt * 32 + ns * 16 + quad * 4 + i > qglob)
                        s[ns][i] = -__builtin_inff();
        }
        // ---- fixed-anchor softmax: establish m once (first tile) ----
        if (kt == kt_begin) {
            float pm = -__builtin_inff();
#pragma unroll
            for (int ns = 0; ns < 2; ns++)
#pragma unroll
                for (int i = 0; i < 4; i++) pm = fmaxf(pm, s[ns][i]);
            pm = fmaxf(pm, __shfl_xor(pm, 16));
            pm = fmaxf(pm, __shfl_xor(pm, 32));
            mi = pm;
        }
        float p[2][4], rs = 0.f;
#pragma unroll
        for (int ns = 0; ns < 2; ns++)
#pragma unroll
            for (int i = 0; i < 4; i++) {
                p[ns][i] = exp2f(s[ns][i] - mi);
                rs += p[ns][i];
            }
        rs += __shfl_xor(rs, 16);
        rs += __shfl_xor(rs, 32);
        li += rs;

        // ---- P -> private per-wave LDS in PV B-operand layout ----
#pragma unroll
        for (int ns = 0; ns < 2; ns++)
#pragma unroll
            for (int i2 = 0; i2 < 2; i2++) {
                bf16x2 d2;
                d2[0] = (__bf16)p[ns][2 * i2];
                d2[1] = (__bf16)p[ns][2 * i2 + 1];
                int off = ((ns * 2 + (quad >> 1)) * 16 + cm) * 8
                          + (quad & 1) * 4 + i2 * 2;
                *(bf16x2*)&ldsP[w][off] = d2;
            }
        // ---- O += V^T-frag x P-frag ----
        bf16x8 pfrag = *(const bf16x8*)&ldsP[w][(quad * 16 + cm) * 8];
        __builtin_amdgcn_s_setprio(1);
#pragma unroll
        for (int nt = 0; nt < 16; nt++) {
            bf16x8 vfr = *(const bf16x8*)&ldsV[(nt * 64 + lane) * 8];
            accO[nt] = MFMA16(vfr, pfrag, accO[nt]);
        }
        __builtin_amdgcn_s_setprio(0);
    }

    // ---- epilogue: coalesced bf16x4 stores + fp32 (m, l) ----
    __bf16* op = Opart + ((size_t)lpid * 64 + w * 16 + cm) * HS_;
#pragma unroll
    for (int nt = 0; nt < 16; nt++) {
        bf16x4 v4;
        v4[0] = (__bf16)accO[nt][0]; v4[1] = (__bf16)accO[nt][1];
        v4[2] = (__bf16)accO[nt][2]; v4[3] = (__bf16)accO[nt][3];
        *(bf16x4*)(op + nt * 16 + quad * 4) = v4;
    }
    if (quad == 0) {
        mpart[lpid * 64 + w * 16 + cm] = mi;
        lpart[lpid * 64 + w * 16 + cm] = li;
    }
}

// ---------------------------------------------------------------------------
// Kernel 3b: combine partials.  Grid (256, 4): block = (b, qb) x 16 rows.
// ---------------------------------------------------------------------------
__global__ __launch_bounds__(256) void flash_combine(const __bf16* __restrict__ Opart,
                                                     const float* __restrict__ mpart,
                                                     const float* __restrict__ lpart,
                                                     float* __restrict__ out) {
    const int b    = blockIdx.x >> 5;
    const int qb   = blockIdx.x & 31;
    const int nc   = (qb >> 2) + 1;
    const int pid0 = b * CHUNKS_PER_BATCH + chunk_cum64(qb);

    const int tid  = threadIdx.x;
    const int col  = (tid & 63) * 4;
    const int r0   = blockIdx.y * 16 + (tid >> 6) * 4;

    f32x4 ms = (f32x4){-__builtin_inff(), -__builtin_inff(),
                       -__builtin_inff(), -__builtin_inff()};
    for (int c = 0; c < nc; c++) {
        f32x4 m4 = *(const f32x4*)(mpart + (pid0 + c) * 64 + r0);
#pragma unroll
        for (int i = 0; i < 4; i++) ms[i] = fmaxf(ms[i], m4[i]);
    }
    f32x4 acc[4];
#pragma unroll
    for (int i = 0; i < 4; i++) acc[i] = (f32x4){0.f, 0.f, 0.f, 0.f};
    f32x4 lt = (f32x4){0.f, 0.f, 0.f, 0.f};
    for (int c = 0; c < nc; c++) {
        f32x4 m4 = *(const f32x4*)(mpart + (pid0 + c) * 64 + r0);
        f32x4 l4 = *(const f32x4*)(lpart + (pid0 + c) * 64 + r0);
#pragma unroll
        for (int i = 0; i < 4; i++) {
            float sc = exp2f(m4[i] - ms[i]);
            lt[i] += l4[i] * sc;
            bf16x4 o = *(const bf16x4*)(Opart
                        + ((size_t)(pid0 + c) * 64 + r0 + i) * HS_ + col);
            acc[i][0] += (float)o[0] * sc; acc[i][1] += (float)o[1] * sc;
            acc[i][2] += (float)o[2] * sc; acc[i][3] += (float)o[3] * sc;
        }
    }
#pragma unroll
    for (int i = 0; i < 4; i++) {
        float inv = 1.0f / lt[i];
        f32x4 res = (f32x4){acc[i][0] * inv, acc[i][1] * inv,
                            acc[i][2] * inv, acc[i][3] * inv};
        *(f32x4*)(out + ((size_t)(b * T_ + qb * 64 + r0 + i)) * HS_ + col) = res;
    }
}

// ---------------------------------------------------------------------------
extern "C" void kernel_launch(void* const* d_in, const int* in_sizes, int n_in,
                              void* d_out, int out_size, void* d_ws, size_t ws_size,
                              hipStream_t stream) {
    const float* x  = (const float*)d_in[0];
    const float* Wq = (const float*)d_in[1];
    const float* Wk = (const float*)d_in[2];
    const float* Wv = (const float*)d_in[3];
    float* out = (float*)d_out;

    char* ws = (char*)d_ws;
    size_t off = 0;
    __bf16* wt_all = (__bf16*)(ws + off); off += 1179648;
    __bf16* qfrag  = (__bf16*)(ws + off); off += 8388608;
    __bf16* kfrag  = (__bf16*)(ws + off); off += 8388608;
    __bf16* vfrag  = (__bf16*)(ws + off); off += 8388608;
    __bf16* xb     = (__bf16*)(ws + off);              // union with Opart
    __bf16* Opart  = (__bf16*)(ws + off); off += (size_t)NSLOT * 64 * HS_ * 2;
    float*  mpart  = (float*)(ws + off);  off += (size_t)NSLOT * 64 * 4;
    float*  lpart  = (float*)(ws + off);

    float qscale = 1.4426950408889634f / sqrtf((float)C_);

    prep_kernel<<<dim3(6432), 256, 0, stream>>>(x, Wq, Wk, Wv, xb, wt_all, qscale);
    proj_kernel<<<dim3(128, 6), 256, 0, stream>>>(xb, wt_all, qfrag, kfrag, vfrag);
    flash_part<<<dim3(NSLOT), 256, 0, stream>>>(qfrag, kfrag, vfrag, Opart, mpart, lpart);
    flash_combine<<<dim3(256, 4), 256, 0, stream>>>(Opart, mpart, lpart, out);
}

// Round 9
// 178.418 us; speedup vs baseline: 1.1328x; 1.0932x over previous
//
#include <hip/hip_runtime.h>
#include <hip/hip_bf16.h>
#include <math.h>

// Problem constants
#define B_  8
#define T_  2048
#define C_  768
#define HS_ 256

// Split-K flash: q-block = 64 rows, k-tile = 32 keys, chunk = 8 k-tiles
// (256 keys). q-block qb (0..31) has 2qb+2 k-tiles; chunks(qb) = (qb>>2)+1;
// per-batch chunk total = 144; blocks = 8 * 144 = 1152.
// R17: R12 body + fine chunks (1152 blocks) + __launch_bounds__(256,3).
// R16's (256,4) crushed VGPR to 64 -> spills (WRITE_SIZE +16.5 MB, FETCH
// +8 MB, MfmaUtil DOWN at higher occupancy). (256,3) restores the proven
// VGPR=84 contract; 84<=128 still lets HW co-resident 4 blocks/CU (LDS
// 4x36=144<=160 KB) -- the bound is an allocator floor, not a residency cap.
#define CHUNKS_PER_BATCH 144
#define NSLOT (CHUNKS_PER_BATCH * B_)   // 1152

typedef float  f32x4  __attribute__((ext_vector_type(4)));
typedef __bf16 bf16x8 __attribute__((ext_vector_type(8)));
typedef __bf16 bf16x4 __attribute__((ext_vector_type(4)));
typedef __bf16 bf16x2 __attribute__((ext_vector_type(2)));

#define MFMA16(a, b, c) __builtin_amdgcn_mfma_f32_16x16x32_bf16((a), (b), (c), 0, 0, 0)

// global->LDS async copy, 16B per lane (dest = wave-uniform base + lane*16)
#define GLOAD_LDS16(gp, lp)                                                     \
    __builtin_amdgcn_global_load_lds(                                           \
        (const __attribute__((address_space(1))) void*)(gp),                    \
        (__attribute__((address_space(3))) void*)(lp), 16, 0, 0)

// cumulative chunk count before q-block qb (8-tile chunks):
// g=qb>>2 -> 2g(g+1) + (qb&3)(g+1)
__device__ __forceinline__ int chunk_cum64(int qb) {
    int g = qb >> 2;
    return 2 * g * (g + 1) + (qb & 3) * (g + 1);
}

// ---------------------------------------------------------------------------
// Kernel 0: prep = x cast (blocks 0..6143) + weight transpose (6144..6431).
// ---------------------------------------------------------------------------
__global__ __launch_bounds__(256) void prep_kernel(const float* __restrict__ x,
                                                   const float* __restrict__ Wq,
                                                   const float* __restrict__ Wk,
                                                   const float* __restrict__ Wv,
                                                   __bf16* __restrict__ xb,
                                                   __bf16* __restrict__ wt_all,
                                                   float qscale) {
    const int bid = blockIdx.x;
    if (bid < 6144) {
        size_t i = ((size_t)bid * 256 + threadIdx.x) * 8;
        f32x4 a = *(const f32x4*)(x + i);
        f32x4 b = *(const f32x4*)(x + i + 4);
        bf16x8 o;
        o[0] = (__bf16)a[0]; o[1] = (__bf16)a[1]; o[2] = (__bf16)a[2]; o[3] = (__bf16)a[3];
        o[4] = (__bf16)b[0]; o[5] = (__bf16)b[1]; o[6] = (__bf16)b[2]; o[7] = (__bf16)b[3];
        *(bf16x8*)(xb + i) = o;
    } else {
        int idx = (bid - 6144) * 256 + threadIdx.x;   // [0, 73728)
        int n   = idx & 255;
        int t   = idx >> 8;          // [0, 288) = mat*96 + k8
        int mat = t / 96;
        int k8  = t - mat * 96;
        const float* W = (mat == 0) ? Wq : ((mat == 1) ? Wk : Wv);
        float scale = (mat == 0) ? qscale : 1.0f;
        bf16x8 o;
#pragma unroll
        for (int j = 0; j < 8; j++)
            o[j] = (__bf16)(W[(k8 * 8 + j) * HS_ + n] * scale);
        *(bf16x8*)&wt_all[((size_t)mat * HS_ + n) * C_ + k8 * 8] = o;
    }
}

// ---------------------------------------------------------------------------
// Kernel 2: fused QKV GEMM. BK=32, double-buffered LDS, one barrier/iter.
//   Q/K tiles: swapped operands (C rows carry d) -> coalesced bf16x4 stores.
// Fragment layouts (element index, all *8 = 8 bf16 per lane slot):
//   Q: ((((b*32+qt)*4 + w16)*8 + ks )*64 + lane)   lane&15 = q, quad = (d>>3)&3, j = d&7
//   K: ((((b*32+kt)*8 + ks )*4 + ns )*64 + lane)   lane&15 = s, quad = (d>>3)&3, j = d&7
//   V: ((((b*32+kt)*2 + ks2)*16 + ntv)*64 + lane)  lane&15 = d, quad = (s>>3)&3, j = s&7
// ---------------------------------------------------------------------------
__global__ __launch_bounds__(256) void proj_kernel(const __bf16* __restrict__ xb,
                                                   const __bf16* __restrict__ wt,
                                                   __bf16* __restrict__ qf_,
                                                   __bf16* __restrict__ kf_,
                                                   __bf16* __restrict__ vf_) {
    __shared__ alignas(16) __bf16 ldsA[2][128 * 32];   // 2 x 8 KB
    __shared__ alignas(16) __bf16 ldsB[2][128 * 32];   // 2 x 8 KB

    const int tid  = threadIdx.x;
    const int w    = tid >> 6;
    const int lane = tid & 63;
    const int cm   = lane & 15;
    const int quad = lane >> 4;
    const int wm   = w & 1;
    const int wn   = w >> 1;
    const int m0   = blockIdx.x * 128;
    const int n0   = blockIdx.y * 128;
    const int mat  = n0 >> 8;                 // 0=Q 1=K 2=V

    f32x4 acc[4][4];
#pragma unroll
    for (int i = 0; i < 4; i++)
#pragma unroll
        for (int j = 0; j < 4; j++) acc[i][j] = (f32x4){0.f, 0.f, 0.f, 0.f};

    // prologue: stage k-iter 0 into buffer 0
#pragma unroll
    for (int h = 0; h < 2; h++) {
        int c = tid + h * 256;   // 512 chunks: row = c>>2, col granule = (c&3)*8
        GLOAD_LDS16(xb + (size_t)(m0 + (c >> 2)) * C_ + (c & 3) * 8, &ldsA[0][c * 8]);
        GLOAD_LDS16(wt + (size_t)(n0 + (c >> 2)) * C_ + (c & 3) * 8, &ldsB[0][c * 8]);
    }

    for (int kt = 0; kt < 24; kt++) {
        const int cur = kt & 1;
        __syncthreads();   // drains vmcnt -> buf[cur] staged; prev reads done

        if (kt < 23) {
            const int k0 = (kt + 1) * 32;
#pragma unroll
            for (int h = 0; h < 2; h++) {
                int c = tid + h * 256;
                GLOAD_LDS16(xb + (size_t)(m0 + (c >> 2)) * C_ + k0 + (c & 3) * 8,
                            &ldsA[cur ^ 1][c * 8]);
                GLOAD_LDS16(wt + (size_t)(n0 + (c >> 2)) * C_ + k0 + (c & 3) * 8,
                            &ldsB[cur ^ 1][c * 8]);
            }
        }

        bf16x8 af[4], bfr[4];
#pragma unroll
        for (int mt = 0; mt < 4; mt++)
            af[mt] = *(const bf16x8*)&ldsA[cur][(wm * 64 + mt * 16 + cm) * 32 + quad * 8];
#pragma unroll
        for (int nt = 0; nt < 4; nt++)
            bfr[nt] = *(const bf16x8*)&ldsB[cur][(wn * 64 + nt * 16 + cm) * 32 + quad * 8];
        if (mat < 2) {
#pragma unroll
            for (int dt = 0; dt < 4; dt++)
#pragma unroll
                for (int qt2 = 0; qt2 < 4; qt2++)
                    acc[dt][qt2] = MFMA16(bfr[dt], af[qt2], acc[dt][qt2]);
        } else {
#pragma unroll
            for (int mt = 0; mt < 4; mt++)
#pragma unroll
                for (int nt = 0; nt < 4; nt++)
                    acc[mt][nt] = MFMA16(af[mt], bfr[nt], acc[mt][nt]);
        }
    }

    const int dBase = (n0 & 255) + wn * 64;
    const int b     = m0 >> 11;
    if (mat < 2) {
        const int rt2 = ((m0 & 2047) >> 6) + wm;   // 64-row tile within batch
        __bf16* dst = (mat == 0) ? qf_ : kf_;
#pragma unroll
        for (int dt = 0; dt < 4; dt++)
#pragma unroll
            for (int qt2 = 0; qt2 < 4; qt2++) {
                int d0    = dBase + dt * 16 + quad * 4;   // d of reg i = d0 + i
                int ksq   = d0 >> 5;
                int quadp = (d0 >> 3) & 3;
                int j0    = d0 & 7;
                size_t addr;
                if (mat == 0)
                    addr = ((((size_t)(b * 32 + rt2) * 4 + qt2) * 8 + ksq) * 64
                            + quadp * 16 + cm) * 8 + j0;
                else
                    addr = ((((size_t)(b * 32 + rt2) * 8 + ksq) * 4 + qt2) * 64
                            + quadp * 16 + cm) * 8 + j0;
                bf16x4 v4;
                v4[0] = (__bf16)acc[dt][qt2][0]; v4[1] = (__bf16)acc[dt][qt2][1];
                v4[2] = (__bf16)acc[dt][qt2][2]; v4[3] = (__bf16)acc[dt][qt2][3];
                *(bf16x4*)(dst + addr) = v4;
            }
    } else {
        const int rt = ((m0 & 2047) + wm * 64) >> 6;
#pragma unroll
        for (int mt = 0; mt < 4; mt++) {
            int ks2   = (mt >> 1) & 1;
            int quadF = (mt & 1) * 2 + (quad >> 1);
            int jb    = (quad & 1) * 4;
#pragma unroll
            for (int nt = 0; nt < 4; nt++) {
                int ntv = (dBase >> 4) + nt;
                size_t idx = ((((size_t)(b * 32 + rt) * 2 + ks2) * 16 + ntv) * 64
                              + quadF * 16 + cm) * 8 + jb;
                bf16x4 v4;
                v4[0] = (__bf16)acc[mt][nt][0]; v4[1] = (__bf16)acc[mt][nt][1];
                v4[2] = (__bf16)acc[mt][nt][2]; v4[3] = (__bf16)acc[mt][nt][3];
                *(bf16x4*)(vf_ + idx) = v4;
            }
        }
    }
}

// ---------------------------------------------------------------------------
// Kernel 3a: split-K causal flash partial — R17 (resubmit): EXACT R12 body
//   AND compile contract (__launch_bounds__(256,3) -> VGPR 84, zero spill),
//   36 KB LDS, single-buffered K/V, 2 barriers/tile, block-shared staging;
//   8-tile (256-key) chunks -> 1152 blocks. 84 VGPR <= 128 and 4x36KB <=
//   160KB permit 4 blocks/CU resident; R12's 16.8% occupancy was grid
//   starvation (640 blocks), fixed by the finer chunking alone.
// ---------------------------------------------------------------------------
__global__ __launch_bounds__(256, 3) void flash_part(const __bf16* __restrict__ qf_,
                                                     const __bf16* __restrict__ kf_,
                                                     const __bf16* __restrict__ vf_,
                                                     __bf16* __restrict__ Opart,
                                                     float* __restrict__ mpart,
                                                     float* __restrict__ lpart) {
    __shared__ alignas(16) __bf16 ldsK[8 * 2 * 64 * 8];   // [ks8][ns2][lane]x8 = 16 KB
    __shared__ alignas(16) __bf16 ldsV[16 * 64 * 8];      // [ntv16][lane]x8  = 16 KB
    __shared__ alignas(16) __bf16 ldsP[4][512];           // per-wave P (1 KB)

    const int tid  = threadIdx.x;
    const int w    = tid >> 6;       // 0..3
    const int lane = tid & 63;
    const int cm   = lane & 15;      // = q column
    const int quad = lane >> 4;

    const int pid  = blockIdx.x;                // [0, 1152)
    const int b    = pid & 7;                   // batch -> XCD spread
    const int r    = (CHUNKS_PER_BATCH - 1) - (pid >> 3);   // heavy chunks first
    int qb = 0, ci = 0;
    {
        int rr = r;
        for (int j = 0; j < 32; j++) {
            int c = (j >> 2) + 1;               // chunks for q-block j
            if (rr < c) { qb = j; ci = rr; break; }
            rr -= c;
        }
    }
    const int lpid = b * CHUNKS_PER_BATCH + r;  // output slot
    const int kt_begin = ci * 8;                        // 32-key tiles
    const int kt_end   = min(kt_begin + 8, 2 * qb + 2);

    // Q fragments (B-operand: lane&15 = q, quad*8+j = d), coalesced loads.
    const __bf16* qp = qf_ + (((size_t)(b * 32 + qb) * 4 + w) * 8) * 512 + lane * 8;
    bf16x8 qf[8];
#pragma unroll
    for (int ks = 0; ks < 8; ks++) qf[ks] = *(const bf16x8*)(qp + ks * 512);

    f32x4 accO[16];   // accO[nt][i]: d = nt*16 + quad*4 + i, q = cm
#pragma unroll
    for (int i = 0; i < 16; i++) accO[i] = (f32x4){0.f, 0.f, 0.f, 0.f};
    float mi = 0.f, li = 0.f;        // mi fixed after first tile

    const int wrow  = qb * 64 + w * 16;
    const int qglob = wrow + cm;

    for (int kt = kt_begin; kt < kt_end; kt++) {
        __syncthreads();   // (A) prior tile's LDS fully consumed

        // ---- stage K (16 KB) + V (16 KB) tile, async ----
        {
            const int kt64 = kt >> 1, kh = kt & 1;
            const __bf16* kgb = kf_ + (((size_t)(b * 32 + kt64) * 8) * 4 + kh * 2) * 512;
#pragma unroll
            for (int h = 0; h < 4; h++) {
                int g = h * 256 + tid;           // 16B slot id, 0..1023
                int ks = g >> 7, sub = g & 127;  // sub = ns2*64 + lane'
                GLOAD_LDS16(kgb + (size_t)ks * 4 * 512 + sub * 8,
                            ldsK + (h * 256 + w * 64) * 8);
            }
            const __bf16* vgb = vf_ + ((size_t)(b * 64 + kt) * 16) * 512;
#pragma unroll
            for (int h = 0; h < 4; h++) {
                int g = h * 256 + tid;           // ntv = g>>6, lane' = g&63
                GLOAD_LDS16(vgb + (size_t)g * 8,
                            ldsV + (h * 256 + w * 64) * 8);
            }
        }
        __syncthreads();   // (B) vmcnt drained -> K/V visible

        // ---- St = K Q^T  (32 s x 16 q per wave) ----
        f32x4 s[2];
#pragma unroll
        for (int i = 0; i < 2; i++) s[i] = (f32x4){0.f, 0.f, 0.f, 0.f};
        __builtin_amdgcn_s_setprio(1);
#pragma unroll
        for (int ns = 0; ns < 2; ns++)
#pragma unroll
            for (int ks = 0; ks < 8; ks++) {
                bf16x8 kfr = *(const bf16x8*)&ldsK[(ks * 2 + ns) * 512 + lane * 8];
                s[ns] = MFMA16(kfr, qf[ks], s[ns]);
            }
        __builtin_amdgcn_s_setprio(0);
        // ---- causal mask ----
        if (kt * 32 + 31 > wrow) {
#pragma unroll
            for (int ns = 0; ns < 2; ns++)
#pragma unroll
                for (int i = 0; i < 4; i++)
                    if (kt * 32 + ns * 16 + quad * 4 + i > qglob)
                        s[ns][i] = -__builtin_inff();
        }
        // ---- fixed-anchor softmax: establish m once (first tile) ----
        if (kt == kt_begin) {
            float pm = -__builtin_inff();
#pragma unroll
            for (int ns = 0; ns < 2; ns++)
#pragma unroll
                for (int i = 0; i < 4; i++) pm = fmaxf(pm, s[ns][i]);
            pm = fmaxf(pm, __shfl_xor(pm, 16));
            pm = fmaxf(pm, __shfl_xor(pm, 32));
            mi = pm;
        }
        float p[2][4], rs = 0.f;
#pragma unroll
        for (int ns = 0; ns < 2; ns++)
#pragma unroll
            for (int i = 0; i < 4; i++) {
                p[ns][i] = exp2f(s[ns][i] - mi);
                rs += p[ns][i];
            }
        rs += __shfl_xor(rs, 16);
        rs += __shfl_xor(rs, 32);
        li += rs;

        // ---- P -> private per-wave LDS in PV B-operand layout ----
#pragma unroll
        for (int ns = 0; ns < 2; ns++)
#pragma unroll
            for (int i2 = 0; i2 < 2; i2++) {
                bf16x2 d2;
                d2[0] = (__bf16)p[ns][2 * i2];
                d2[1] = (__bf16)p[ns][2 * i2 + 1];
                int off = ((ns * 2 + (quad >> 1)) * 16 + cm) * 8
                          + (quad & 1) * 4 + i2 * 2;
                *(bf16x2*)&ldsP[w][off] = d2;
            }
        // ---- O += V^T-frag x P-frag ----
        bf16x8 pfrag = *(const bf16x8*)&ldsP[w][(quad * 16 + cm) * 8];
        __builtin_amdgcn_s_setprio(1);
#pragma unroll
        for (int nt = 0; nt < 16; nt++) {
            bf16x8 vfr = *(const bf16x8*)&ldsV[(nt * 64 + lane) * 8];
            accO[nt] = MFMA16(vfr, pfrag, accO[nt]);
        }
        __builtin_amdgcn_s_setprio(0);
    }

    // ---- epilogue: coalesced bf16x4 stores + fp32 (m, l) ----
    __bf16* op = Opart + ((size_t)lpid * 64 + w * 16 + cm) * HS_;
#pragma unroll
    for (int nt = 0; nt < 16; nt++) {
        bf16x4 v4;
        v4[0] = (__bf16)accO[nt][0]; v4[1] = (__bf16)accO[nt][1];
        v4[2] = (__bf16)accO[nt][2]; v4[3] = (__bf16)accO[nt][3];
        *(bf16x4*)(op + nt * 16 + quad * 4) = v4;
    }
    if (quad == 0) {
        mpart[lpid * 64 + w * 16 + cm] = mi;
        lpart[lpid * 64 + w * 16 + cm] = li;
    }
}

// ---------------------------------------------------------------------------
// Kernel 3b: combine partials.  Grid (256, 4): block = (b, qb) x 16 rows.
// ---------------------------------------------------------------------------
__global__ __launch_bounds__(256) void flash_combine(const __bf16* __restrict__ Opart,
                                                     const float* __restrict__ mpart,
                                                     const float* __restrict__ lpart,
                                                     float* __restrict__ out) {
    const int b    = blockIdx.x >> 5;
    const int qb   = blockIdx.x & 31;
    const int nc   = (qb >> 2) + 1;
    const int pid0 = b * CHUNKS_PER_BATCH + chunk_cum64(qb);

    const int tid  = threadIdx.x;
    const int col  = (tid & 63) * 4;
    const int r0   = blockIdx.y * 16 + (tid >> 6) * 4;

    f32x4 ms = (f32x4){-__builtin_inff(), -__builtin_inff(),
                       -__builtin_inff(), -__builtin_inff()};
    for (int c = 0; c < nc; c++) {
        f32x4 m4 = *(const f32x4*)(mpart + (pid0 + c) * 64 + r0);
#pragma unroll
        for (int i = 0; i < 4; i++) ms[i] = fmaxf(ms[i], m4[i]);
    }
    f32x4 acc[4];
#pragma unroll
    for (int i = 0; i < 4; i++) acc[i] = (f32x4){0.f, 0.f, 0.f, 0.f};
    f32x4 lt = (f32x4){0.f, 0.f, 0.f, 0.f};
    for (int c = 0; c < nc; c++) {
        f32x4 m4 = *(const f32x4*)(mpart + (pid0 + c) * 64 + r0);
        f32x4 l4 = *(const f32x4*)(lpart + (pid0 + c) * 64 + r0);
#pragma unroll
        for (int i = 0; i < 4; i++) {
            float sc = exp2f(m4[i] - ms[i]);
            lt[i] += l4[i] * sc;
            bf16x4 o = *(const bf16x4*)(Opart
                        + ((size_t)(pid0 + c) * 64 + r0 + i) * HS_ + col);
            acc[i][0] += (float)o[0] * sc; acc[i][1] += (float)o[1] * sc;
            acc[i][2] += (float)o[2] * sc; acc[i][3] += (float)o[3] * sc;
        }
    }
#pragma unroll
    for (int i = 0; i < 4; i++) {
        float inv = 1.0f / lt[i];
        f32x4 res = (f32x4){acc[i][0] * inv, acc[i][1] * inv,
                            acc[i][2] * inv, acc[i][3] * inv};
        *(f32x4*)(out + ((size_t)(b * T_ + qb * 64 + r0 + i)) * HS_ + col) = res;
    }
}

// ---------------------------------------------------------------------------
extern "C" void kernel_launch(void* const* d_in, const int* in_sizes, int n_in,
                              void* d_out, int out_size, void* d_ws, size_t ws_size,
                              hipStream_t stream) {
    const float* x  = (const float*)d_in[0];
    const float* Wq = (const float*)d_in[1];
    const float* Wk = (const float*)d_in[2];
    const float* Wv = (const float*)d_in[3];
    float* out = (float*)d_out;

    char* ws = (char*)d_ws;
    size_t off = 0;
    __bf16* wt_all = (__bf16*)(ws + off); off += 1179648;
    __bf16* qfrag  = (__bf16*)(ws + off); off += 8388608;
    __bf16* kfrag  = (__bf16*)(ws + off); off += 8388608;
    __bf16* vfrag  = (__bf16*)(ws + off); off += 8388608;
    __bf16* xb     = (__bf16*)(ws + off);              // union with Opart
    __bf16* Opart  = (__bf16*)(ws + off); off += (size_t)NSLOT * 64 * HS_ * 2;
    float*  mpart  = (float*)(ws + off);  off += (size_t)NSLOT * 64 * 4;
    float*  lpart  = (float*)(ws + off);

    float qscale = 1.4426950408889634f / sqrtf((float)C_);

    prep_kernel<<<dim3(6432), 256, 0, stream>>>(x, Wq, Wk, Wv, xb, wt_all, qscale);
    proj_kernel<<<dim3(128, 6), 256, 0, stream>>>(xb, wt_all, qfrag, kfrag, vfrag);
    flash_part<<<dim3(NSLOT), 256, 0, stream>>>(qfrag, kfrag, vfrag, Opart, mpart, lpart);
    flash_combine<<<dim3(256, 4), 256, 0, stream>>>(Opart, mpart, lpart, out);
}